// Round 7
// baseline (9351.543 us; speedup 1.0000x reference)
//
#include <hip/hip_runtime.h>
#include <hip/hip_fp16.h>
#include <math.h>

#define SEQ    8192
#define EMBD   256
#define HD     128
#define GATES  512
#define NTAGS  14
#define TAG_START 12
#define TAG_STOP  13
#define NEGV   (-10000.0f)

// ---- ws layout (float offsets) ----
static constexpr size_t OFF_X     = 0;                               // [SEQ][EMBD]
static constexpr size_t OFF_WT    = OFF_X + (size_t)SEQ * EMBD;      // [EMBD][1024]
static constexpr size_t OFF_BSUM  = OFF_WT + (size_t)EMBD * 1024;    // [1024]
static constexpr size_t OFF_GF    = OFF_BSUM + 1024;                 // [SEQ+4][GATES] quad-layout
static constexpr size_t OFF_GB    = OFF_GF + (size_t)(SEQ + 4) * GATES;
static constexpr size_t OFF_HF    = OFF_GB + (size_t)(SEQ + 4) * GATES; // [SEQ][HD]
static constexpr size_t OFF_HB    = OFF_HF + (size_t)SEQ * HD;          // [SEQ][HD]
static constexpr size_t OFF_FEATS = OFF_HB + (size_t)SEQ * HD;          // [SEQ+8][16]
static constexpr size_t OFF_BP    = OFF_FEATS + (size_t)(SEQ + 8) * 16; // uchar[SEQ][16]
static constexpr size_t OFF_AC    = OFF_BP + (size_t)SEQ * 16 / 4;      // [64][14*16+pad] chunk matrices
static constexpr size_t OFF_FVB   = OFF_AC + (size_t)64 * 256;          // [64][16] boundary fv
static constexpr size_t OFF_SB    = OFF_FVB + 1024;                     // [4] best-tag etc.

#define LOG2E  1.4426950408889634f
#define LOG2E2 2.8853900817779268f

__device__ __forceinline__ float fast_rcp(float x) { return __builtin_amdgcn_rcpf(x); }
__device__ __forceinline__ float bcast_lane(float x, int lane) {
  return __int_as_float(__builtin_amdgcn_readlane(__float_as_int(x), lane));
}
__device__ __forceinline__ float max3f(float a, float b, float c) {
  return fmaxf(fmaxf(a, b), c);   // -> v_max3_f32
}
// max over s[0..13] via max3 tree (exact, order-independent)
__device__ __forceinline__ float max14(const float s[NTAGS]) {
  float m0 = max3f(s[0], s[1], s[2]);
  float m1 = max3f(s[3], s[4], s[5]);
  float m2 = max3f(s[6], s[7], s[8]);
  float m3 = max3f(s[9], s[10], s[11]);
  float m4 = fmaxf(s[12], s[13]);
  return max3f(max3f(m0, m1, m2), m3, m4);
}
// DPP quad_perm: returns the quad-permuted value (pure VALU, no LDS)
template<int CTRL>
__device__ __forceinline__ float quad_dpp(float x) {
  int xi = __float_as_int(x);
  int r = __builtin_amdgcn_update_dpp(xi, xi, CTRL, 0xF, 0xF, false);
  return __int_as_float(r);
}

// barrier that waits LDS only (lgkmcnt), NOT vmcnt -> global prefetch stays in flight
__device__ __forceinline__ void lds_barrier() {
  __builtin_amdgcn_sched_barrier(0);
  asm volatile("s_waitcnt lgkmcnt(0)" ::: "memory");
  __builtin_amdgcn_s_barrier();
  __builtin_amdgcn_sched_barrier(0);
}

// argmax over 14 values, first-index tie-break (matches jnp.argmax)
__device__ __forceinline__ void argmax14(const float s[NTAGS], float& bv, int& bi) {
#define MRG(va, ia, vb, ib, vo, io) { bool c_ = (vb) > (va); (vo) = c_ ? (vb) : (va); (io) = c_ ? (ib) : (ia); }
  float v0, v1, v2, v3, v4, v5, v6; int i0, i1, i2, i3, i4, i5, i6;
  MRG(s[0], 0, s[1], 1, v0, i0); MRG(s[2], 2, s[3], 3, v1, i1);
  MRG(s[4], 4, s[5], 5, v2, i2); MRG(s[6], 6, s[7], 7, v3, i3);
  MRG(s[8], 8, s[9], 9, v4, i4); MRG(s[10], 10, s[11], 11, v5, i5);
  MRG(s[12], 12, s[13], 13, v6, i6);
  float w0, w1, w2; int j0, j1, j2;
  MRG(v0, i0, v1, i1, w0, j0); MRG(v2, i2, v3, i3, w1, j1); MRG(v4, i4, v5, i5, w2, j2);
  float x0, x1; int y0, y1;
  MRG(w0, j0, w1, j1, x0, y0); MRG(w2, j2, v6, i6, x1, y1);
  MRG(x0, y0, x1, y1, bv, bi);
#undef MRG
}

// ---------------- prep: W transpose-pack (quad-permuted cols) + bias sums ----------------
// column c (quad layout) -> original gate row src = (c&3)*HD + (c>>2)
__global__ void prep_k(const float* __restrict__ wihf, const float* __restrict__ wihb,
                       const float* __restrict__ bihf, const float* __restrict__ bhhf,
                       const float* __restrict__ bihb, const float* __restrict__ bhhb,
                       float* __restrict__ WT, float* __restrict__ bsum) {
  if (blockIdx.x < 1024) {
    int e = blockIdx.x * 256 + threadIdx.x;     // e over [EMBD*1024)
    int k = e >> 10, c = e & 1023;
    int cq = c & 511;
    int src = (cq & 3) * HD + (cq >> 2);
    WT[e] = (c < GATES) ? wihf[(size_t)src * EMBD + k] : wihb[(size_t)src * EMBD + k];
  } else {
    for (int i = 0; i < 4; ++i) {
      int c = threadIdx.x + i * 256;
      int cq = c & 511;
      int src = (cq & 3) * HD + (cq >> 2);
      bsum[c] = (c < GATES) ? (bihf[src] + bhhf[src]) : (bihb[src] + bhhb[src]);
    }
  }
}

// ---------------- embedding gather ----------------
__global__ void gather_k(const int* __restrict__ sent, const float* __restrict__ emb,
                         float* __restrict__ X) {
  int t = blockIdx.x;
  int row = sent[t];
  ((float4*)(X + (size_t)t * EMBD))[threadIdx.x] =
      ((const float4*)(emb + (size_t)row * EMBD))[threadIdx.x];
}

// ---------------- input-projection GEMM: G = X @ W^T + bsum ----------------
__global__ __launch_bounds__(256) void gemm_k(const float* __restrict__ X,
                                              const float* __restrict__ WT,
                                              const float* __restrict__ bsum,
                                              float* __restrict__ Gf, float* __restrict__ Gb) {
  __shared__ __align__(16) float As[32][68];   // [k][m], padded stride
  __shared__ __align__(16) float Bs[32][64];   // [k][n]
  const int tid = threadIdx.x;
  const int cb = blockIdx.x * 64;              // 0..960
  const int tb = blockIdx.y * 64;
  const bool flip = (cb >= GATES);
  const int ty = tid >> 4, tx = tid & 15;
  float acc[4][4] = {};

  const int r  = tid >> 2;                     // A-stage: row 0..63
  const int kq = (tid & 3) * 8;                // 8 k's
  const int kB = tid >> 3;                     // B-stage: k 0..31
  const int n8 = (tid & 7) * 8;

  const int trow = tb + r;
  const int src = flip ? (SEQ - 1 - trow) : trow;

  for (int k0 = 0; k0 < EMBD; k0 += 32) {
    const float* xp = X + (size_t)src * EMBD + k0 + kq;
    float4 xa = *(const float4*)xp;
    float4 xb = *(const float4*)(xp + 4);
    As[kq + 0][r] = xa.x; As[kq + 1][r] = xa.y; As[kq + 2][r] = xa.z; As[kq + 3][r] = xa.w;
    As[kq + 4][r] = xb.x; As[kq + 5][r] = xb.y; As[kq + 6][r] = xb.z; As[kq + 7][r] = xb.w;
    const float* wp = WT + (size_t)(k0 + kB) * 1024 + cb + n8;
    *(float4*)&Bs[kB][n8]     = *(const float4*)wp;
    *(float4*)&Bs[kB][n8 + 4] = *(const float4*)(wp + 4);
    __syncthreads();
    #pragma unroll
    for (int k = 0; k < 32; ++k) {
      float4 av = *(const float4*)&As[k][ty * 4];
      float4 bv = *(const float4*)&Bs[k][tx * 4];
      acc[0][0] = fmaf(av.x, bv.x, acc[0][0]); acc[0][1] = fmaf(av.x, bv.y, acc[0][1]);
      acc[0][2] = fmaf(av.x, bv.z, acc[0][2]); acc[0][3] = fmaf(av.x, bv.w, acc[0][3]);
      acc[1][0] = fmaf(av.y, bv.x, acc[1][0]); acc[1][1] = fmaf(av.y, bv.y, acc[1][1]);
      acc[1][2] = fmaf(av.y, bv.z, acc[1][2]); acc[1][3] = fmaf(av.y, bv.w, acc[1][3]);
      acc[2][0] = fmaf(av.z, bv.x, acc[2][0]); acc[2][1] = fmaf(av.z, bv.y, acc[2][1]);
      acc[2][2] = fmaf(av.z, bv.z, acc[2][2]); acc[2][3] = fmaf(av.z, bv.w, acc[2][3]);
      acc[3][0] = fmaf(av.w, bv.x, acc[3][0]); acc[3][1] = fmaf(av.w, bv.y, acc[3][1]);
      acc[3][2] = fmaf(av.w, bv.z, acc[3][2]); acc[3][3] = fmaf(av.w, bv.w, acc[3][3]);
    }
    __syncthreads();
  }
  float4 bz = *(const float4*)&bsum[cb + tx * 4];
  #pragma unroll
  for (int mm = 0; mm < 4; ++mm) {
    int t = tb + ty * 4 + mm;
    float4 v = { acc[mm][0] + bz.x, acc[mm][1] + bz.y, acc[mm][2] + bz.z, acc[mm][3] + bz.w };
    if (!flip) *(float4*)&Gf[(size_t)t * GATES + cb + tx * 4] = v;
    else       *(float4*)&Gb[(size_t)t * GATES + (cb - GATES) + tx * 4] = v;
  }
}

// ---------------- the serial LSTM recurrence: BOTH directions in ONE block ----------------
// 1024 threads: tid>>9 = direction, g=tid&511 -> hidden j=g>>2, quad-slot q=g&3.
// Two independent dep chains per SIMD (4 waves: 2 fwd + 2 bwd) hide the per-step
// latency stall. Global h-stores go through a double-buffered LDS ring flushed
// as float4 every 16 steps. 3-deep G prefetch rides across raw lds_barriers.
__global__ __launch_bounds__(1024, 4) void lstm_k(
    const float* __restrict__ whhf, const float* __restrict__ whhb,
    const float* __restrict__ Gf, const float* __restrict__ Gb,
    float* __restrict__ HF, float* __restrict__ HB) {
  const int tid = threadIdx.x;
  const int dir = tid >> 9;
  const int g = tid & 511;
  const int j = g >> 2;         // hidden index 0..127
  const int q = g & 3;          // k-quarter AND own-gate index (i,f,g,o)
  const bool q0 = (q == 0);
  const float* __restrict__ G   = dir ? Gb : Gf;
  float* __restrict__ Hout      = dir ? HB : HF;
  const float* __restrict__ whh = dir ? whhb : whhf;

  // weights: w2[gate][kk] = (W[gate*HD+j][q*32+2kk], W[..][q*32+2kk+1]) as half2
  __half2 w2[4][16];
  #pragma unroll
  for (int gi = 0; gi < 4; ++gi) {
    const float* wr = whh + (size_t)(gi * HD + j) * HD + q * 32;
    #pragma unroll
    for (int kk = 0; kk < 16; ++kk)
      w2[gi][kk] = __halves2half2(__float2half_rn(wr[2 * kk]),
                                  __float2half_rn(wr[2 * kk + 1]));
  }

  // unified activation for own gate q: sigmoid, except gate 2 = tanh = 2*sig(2x)-1
  const float mm = (q == 2) ? -LOG2E2 : -LOG2E;
  const float aa = (q == 2) ? 2.0f : 1.0f;
  const float bb = (q == 2) ? -1.0f : 0.0f;

  // h in f16: [dir][quarter(padded QS)] ; double-buffered
  constexpr int QS = 48;
  __shared__ __align__(16) __half hshA[2 * 4 * QS], hshB[2 * 4 * QS];
  // h output ring: [par][dir][16 steps][HD] f32, flushed as float4 every 16 steps
  __shared__ __align__(16) float ring[2][2][16][HD];   // 32 KB
  if (tid < 2 * 4 * QS) hshA[tid] = __float2half_rn(0.0f);

  float cst = 0.0f;

  // 3-deep prefetch of per-step input projection (quad layout, coalesced)
  const float* gp = G + g;
  float gc  = gp[0];
  float gn1 = gp[GATES];
  float gn2 = gp[2 * GATES];
  gp += 3 * GATES;

  const int hbase = dir * 4 * QS;
  const int wslot = hbase + (j >> 5) * QS + (j & 31);
  const int rdoff = hbase + q * QS;
  float* const ringd = &ring[0][dir][0][0];   // + par*(2*16*HD) + slot*HD

  lds_barrier();

  auto step = [&](const __half* hrd, __half* hwr, float* ringrow) {
    float gcur = gc; gc = gn1; gn1 = gn2; gn2 = *gp; gp += GATES;

    // read own 32-half quarter of h: 4 x b128 (16-lane same-address broadcast)
    const float4* hq = (const float4*)(hrd + rdoff);
    float4 r0 = hq[0], r1 = hq[1], r2 = hq[2], r3 = hq[3];
    const __half2* h0 = (const __half2*)&r0;
    const __half2* h1 = (const __half2*)&r1;
    const __half2* h2 = (const __half2*)&r2;
    const __half2* h3 = (const __half2*)&r3;

    __half2 z2 = __float2half2_rn(0.0f);
    __half2 a0 = z2, a1 = z2, a2 = z2, a3 = z2;
    #pragma unroll
    for (int i = 0; i < 4; ++i) {
      a0 = __hfma2(w2[0][i], h0[i], a0);  a1 = __hfma2(w2[1][i], h0[i], a1);
      a2 = __hfma2(w2[2][i], h0[i], a2);  a3 = __hfma2(w2[3][i], h0[i], a3);
      a0 = __hfma2(w2[0][4 + i], h1[i], a0);  a1 = __hfma2(w2[1][4 + i], h1[i], a1);
      a2 = __hfma2(w2[2][4 + i], h1[i], a2);  a3 = __hfma2(w2[3][4 + i], h1[i], a3);
      a0 = __hfma2(w2[0][8 + i], h2[i], a0);  a1 = __hfma2(w2[1][8 + i], h2[i], a1);
      a2 = __hfma2(w2[2][8 + i], h2[i], a2);  a3 = __hfma2(w2[3][8 + i], h2[i], a3);
      a0 = __hfma2(w2[0][12 + i], h3[i], a0); a1 = __hfma2(w2[1][12 + i], h3[i], a1);
      a2 = __hfma2(w2[2][12 + i], h3[i], a2); a3 = __hfma2(w2[3][12 + i], h3[i], a3);
    }
    float p0 = __low2float(a0) + __high2float(a0);
    float p1 = __low2float(a1) + __high2float(a1);
    float p2 = __low2float(a2) + __high2float(a2);
    float p3 = __low2float(a3) + __high2float(a3);

    // quad butterfly all-reduce (each gate sum completed in every lane)
    p0 += quad_dpp<0xB1>(p0); p1 += quad_dpp<0xB1>(p1);
    p2 += quad_dpp<0xB1>(p2); p3 += quad_dpp<0xB1>(p3);
    p0 += quad_dpp<0x4E>(p0); p1 += quad_dpp<0x4E>(p1);
    p2 += quad_dpp<0x4E>(p2); p3 += quad_dpp<0x4E>(p3);

    // lane q owns gate q
    float t0 = (q & 1) ? p1 : p0;
    float t1 = (q & 1) ? p3 : p2;
    float pre = ((q & 2) ? t1 : t0) + gcur;
    float act = fmaf(aa, fast_rcp(1.0f + exp2f(pre * mm)), bb);

    float i_ = quad_dpp<0x00>(act);
    float f_ = quad_dpp<0x55>(act);
    float g_ = quad_dpp<0xAA>(act);
    float o_ = quad_dpp<0xFF>(act);
    cst = fmaf(f_, cst, i_ * g_);
    float th = fmaf(2.0f, fast_rcp(1.0f + exp2f(cst * -LOG2E2)), -1.0f);
    float hj = o_ * th;
    if (q0) { hwr[wslot] = __float2half_rn(hj); ringrow[j] = hj; }
    lds_barrier();   // the ONLY barrier per step
  };

  // flush vars (hoisted): each thread moves one float4 of its own dir per group
  const int fe = (tid & 511) << 2;         // element 0..2044 within [16][HD] group
  const int ftl = fe >> 7;                 // local step 0..15
  const int fjj = fe & 127;

  int par = 0;
  for (int tg = 0; tg < SEQ; tg += 16) {
    float* rb = ringd + par * (2 * 16 * HD);
    #pragma unroll
    for (int u = 0; u < 8; ++u) {
      step(hshA, hshB, rb + (2 * u) * HD);
      step(hshB, hshA, rb + (2 * u + 1) * HD);
    }
    // flush group (ring[par] complete & visible after the last lds_barrier);
    // next group writes ring[par^1] -> no race, no extra barrier
    float4 v = *(const float4*)(rb + fe);
    size_t row = dir ? (size_t)(SEQ - 1 - tg - ftl) : (size_t)(tg + ftl);
    *(float4*)(Hout + row * HD + fjj) = v;
    par ^= 1;
  }
}

// ---------------- tag-space projection: feats = [hf|hb] @ w_tag^T + b_tag ----------------
__global__ void feats_k(const float* __restrict__ HF, const float* __restrict__ HB,
                        const float* __restrict__ wtag, const float* __restrict__ btag,
                        float* __restrict__ feats) {
  const int t = blockIdx.x, l = threadIdx.x;   // 64 lanes
  float2 a = ((const float2*)(HF + (size_t)t * HD))[l];
  float2 b = ((const float2*)(HB + (size_t)t * HD))[l];
  float p[NTAGS];
  #pragma unroll
  for (int n = 0; n < NTAGS; ++n) {
    const float* wr = wtag + (size_t)n * 256;
    float2 w0 = ((const float2*)wr)[l];
    float2 w1 = ((const float2*)(wr + HD))[l];
    p[n] = a.x * w0.x + a.y * w0.y + b.x * w1.x + b.y * w1.y;
  }
  #pragma unroll
  for (int n = 0; n < NTAGS; ++n) {
    float v = p[n];
    for (int off = 32; off > 0; off >>= 1) v += __shfl_down(v, off);
    if (l == 0) feats[(size_t)t * 16 + n] = v + btag[n];
  }
}

// ---------------- Viterbi, parallel-scan formulation ----------------
// vit_a: per chunk c (64 chunks x 128 steps), compose the max-plus transfer
// matrix A_c[n][p] = best score of any path entering the chunk at tag p and
// leaving at tag n (feats of all chunk steps + transitions included).
__global__ __launch_bounds__(256) void vit_a(const float* __restrict__ feats,
                                             const float* __restrict__ trans,
                                             float* __restrict__ Ac) {
  const int c = blockIdx.x;
  const int tid = threadIdx.x;
  const int n = tid % NTAGS, p = tid / NTAGS;
  const bool act = tid < NTAGS * NTAGS;
  __shared__ __align__(16) float fl[128][16];   // chunk feats
  __shared__ float Ab[2][NTAGS][17];            // stride-17: conflict-light

  const float4* fsrc = (const float4*)(feats + (size_t)c * 128 * 16);
  #pragma unroll
  for (int i = 0; i < 2; ++i)
    ((float4*)&fl[0][0])[tid + i * 256] = fsrc[tid + i * 256];

  float Tr[NTAGS];
  if (act) {
    #pragma unroll
    for (int q = 0; q < NTAGS; ++q) Tr[q] = trans[n * NTAGS + q];
  }
  __syncthreads();
  if (act) Ab[0][n][p] = Tr[p] + fl[0][n];      // first step: A = M_{t0}
  __syncthreads();

  int cur = 0;
  for (int tl = 1; tl < 128; ++tl) {
    if (act) {
      float s[NTAGS];
      #pragma unroll
      for (int q = 0; q < NTAGS; ++q) s[q] = Tr[q] + Ab[cur][q][p];
      Ab[cur ^ 1][n][p] = max14(s) + fl[tl][n];
    }
    __syncthreads();
    cur ^= 1;
  }
  if (act) Ac[(size_t)c * 256 + n * 16 + p] = Ab[cur][n][p];
}

// vit_b: serial over 64 chunk boundaries (1 wave): store fv at each chunk
// start, then terminal score + best tag.
__global__ void vit_b(const float* __restrict__ trans, const float* __restrict__ Ac,
                      float* __restrict__ fvb, float* __restrict__ out,
                      float* __restrict__ sb) {
  const int n = threadIdx.x;
  const bool act = n < NTAGS;
  float fv = (n == TAG_START) ? 0.0f : NEGV;
  for (int c = 0; c < 64; ++c) {
    if (act) fvb[c * 16 + n] = fv;
    float Ar[NTAGS];
    #pragma unroll
    for (int p = 0; p < NTAGS; ++p) Ar[p] = act ? Ac[(size_t)c * 256 + n * 16 + p] : NEGV;
    float s[NTAGS];
    #pragma unroll
    for (int p = 0; p < NTAGS; ++p) s[p] = Ar[p] + bcast_lane(fv, p);
    float nf = max14(s);
    fv = act ? nf : NEGV;
  }
  float tn = fv + (act ? trans[TAG_STOP * NTAGS + n] : NEGV);
  float tv[NTAGS];
  #pragma unroll
  for (int p = 0; p < NTAGS; ++p) tv[p] = bcast_lane(tn, p);
  if (n == 0) {
    float bv; int bi;
    argmax14(tv, bv, bi);
    out[0] = bv;                       // score
    ((int*)sb)[0] = bi;                // best terminal tag
  }
}

// vit_c: 64 chunks in parallel re-run the exact forward recurrence from the
// chunk-boundary fv, emitting backpointers (same code as the old serial pass).
__global__ void vit_c(const float* __restrict__ feats, const float* __restrict__ trans,
                      const float* __restrict__ fvb, unsigned char* __restrict__ bpg) {
  const int c = blockIdx.x;
  const int n = threadIdx.x;
  const bool act = n < NTAGS;
  float Tn[NTAGS];
  #pragma unroll
  for (int p = 0; p < NTAGS; ++p) Tn[p] = act ? trans[n * NTAGS + p] : 0.0f;
  float fv = act ? fvb[c * 16 + n] : NEGV;
  const int t0 = c * 128;

  float fbuf[8];
  #pragma unroll
  for (int u = 0; u < 8; ++u) fbuf[u] = act ? feats[(size_t)(t0 + u) * 16 + n] : 0.0f;

  for (int tb = 0; tb < 128; tb += 8) {
    #pragma unroll
    for (int u = 0; u < 8; ++u) {
      const int t = t0 + tb + u;
      float ftc = fbuf[u];
      fbuf[u] = act ? feats[(size_t)(t + 8) * 16 + n] : 0.0f;   // padded rows
      float s[NTAGS];
      #pragma unroll
      for (int p = 0; p < NTAGS; ++p) s[p] = bcast_lane(fv, p) + Tn[p];
      float bv = max14(s);
      fv = bv + ftc;
      int bi = 13;
      #pragma unroll
      for (int p = 12; p >= 0; --p) bi = (s[p] == bv) ? p : bi;
      if (act) bpg[(size_t)t * 16 + n] = (unsigned char)bi;
    }
  }
}

// vit_d: chunked parallel backtrace (unchanged logic)
__global__ __launch_bounds__(1024) void vit_d(const unsigned char* __restrict__ bpg,
                                              const float* __restrict__ sb,
                                              float* __restrict__ out) {
  __shared__ int sh_M[64 * 16];
  __shared__ int sh_B[64];
  const int tid = threadIdx.x;
  {                               // phase B: compose 128-step backpointer maps per chunk
    const int c = tid >> 4, k = tid & 15;
    if (c >= 1 && c < 64 && k < NTAGS) {
      int x = k;
      for (int i = 127; i >= 0; --i) x = bpg[((size_t)(c * 128 + i)) * 16 + x];
      sh_M[c * 16 + k] = x;
    }
  }
  __syncthreads();
  if (tid == 0) {                 // phase C: serial walk over 64 chunk boundaries
    int b = ((const int*)sb)[0];
    sh_B[63] = b;
    for (int c = 63; c >= 1; --c) { b = sh_M[c * 16 + b]; sh_B[c - 1] = b; }
  }
  __syncthreads();
  if (tid < 64) {                 // phase D: chunks re-walk in parallel, emit path
    const int c = tid;
    int x = sh_B[c];
    out[1 + c * 128 + 127] = (float)x;
    for (int i = 127; i >= 1; --i) {
      x = bpg[((size_t)(c * 128 + i)) * 16 + x];
      out[1 + c * 128 + i - 1] = (float)x;
    }
  }
}

extern "C" void kernel_launch(void* const* d_in, const int* in_sizes, int n_in,
                              void* d_out, int out_size, void* d_ws, size_t ws_size,
                              hipStream_t stream) {
  (void)in_sizes; (void)n_in; (void)out_size; (void)ws_size;
  const int*   sent = (const int*)d_in[0];
  const float* emb  = (const float*)d_in[1];
  const float* wihf = (const float*)d_in[2];
  const float* whhf = (const float*)d_in[3];
  const float* bihf = (const float*)d_in[4];
  const float* bhhf = (const float*)d_in[5];
  const float* wihb = (const float*)d_in[6];
  const float* whhb = (const float*)d_in[7];
  const float* bihb = (const float*)d_in[8];
  const float* bhhb = (const float*)d_in[9];
  const float* wtag = (const float*)d_in[10];
  const float* btag = (const float*)d_in[11];
  const float* trans = (const float*)d_in[12];

  float* ws = (float*)d_ws;
  float* X    = ws + OFF_X;
  float* WT   = ws + OFF_WT;
  float* BS   = ws + OFF_BSUM;
  float* Gf   = ws + OFF_GF;
  float* Gb   = ws + OFF_GB;
  float* HF   = ws + OFF_HF;
  float* HB   = ws + OFF_HB;
  float* FE   = ws + OFF_FEATS;
  unsigned char* bpg = (unsigned char*)(ws + OFF_BP);
  float* AC   = ws + OFF_AC;
  float* FVB  = ws + OFF_FVB;
  float* SB   = ws + OFF_SB;
  float* out = (float*)d_out;

  prep_k<<<1025, 256, 0, stream>>>(wihf, wihb, bihf, bhhf, bihb, bhhb, WT, BS);
  gather_k<<<SEQ, 64, 0, stream>>>(sent, emb, X);
  gemm_k<<<dim3(16, 128), 256, 0, stream>>>(X, WT, BS, Gf, Gb);
  lstm_k<<<1, 1024, 0, stream>>>(whhf, whhb, Gf, Gb, HF, HB);
  feats_k<<<SEQ, 64, 0, stream>>>(HF, HB, wtag, btag, FE);
  vit_a<<<64, 256, 0, stream>>>(FE, trans, AC);
  vit_b<<<1, 64, 0, stream>>>(trans, AC, FVB, out, SB);
  vit_c<<<64, 64, 0, stream>>>(FE, trans, FVB, bpg);
  vit_d<<<1, 1024, 0, stream>>>(bpg, SB, out);
}

// Round 8
// 5606.173 us; speedup vs baseline: 1.6681x; 1.6681x over previous
//
#include <hip/hip_runtime.h>
#include <hip/hip_fp16.h>
#include <math.h>

#define SEQ    8192
#define EMBD   256
#define HD     128
#define GATES  512
#define NTAGS  14
#define TAG_START 12
#define TAG_STOP  13
#define NEGV   (-10000.0f)
#define GRP    16            // LSTM steps per G-staging group

// ---- ws layout (float offsets) ----
static constexpr size_t OFF_X     = 0;                               // [SEQ][EMBD]
static constexpr size_t OFF_WT    = OFF_X + (size_t)SEQ * EMBD;      // [EMBD][1024]
static constexpr size_t OFF_BSUM  = OFF_WT + (size_t)EMBD * 1024;    // [1024]
static constexpr size_t OFF_GF    = OFF_BSUM + 1024;                 // [SEQ+4][GATES] quad-layout
static constexpr size_t OFF_GB    = OFF_GF + (size_t)(SEQ + 4) * GATES;
static constexpr size_t OFF_HF    = OFF_GB + (size_t)(SEQ + 4) * GATES; // [SEQ][HD]
static constexpr size_t OFF_HB    = OFF_HF + (size_t)SEQ * HD;          // [SEQ][HD]
static constexpr size_t OFF_FEATS = OFF_HB + (size_t)SEQ * HD;          // [SEQ+8][16]
static constexpr size_t OFF_BP    = OFF_FEATS + (size_t)(SEQ + 8) * 16; // uchar[SEQ][16]
static constexpr size_t OFF_AC    = OFF_BP + (size_t)SEQ * 16 / 4;      // [64][256] chunk matrices
static constexpr size_t OFF_FVB   = OFF_AC + (size_t)64 * 256;          // [64][16] boundary fv
static constexpr size_t OFF_SB    = OFF_FVB + 1024;                     // [4] best-tag etc.

#define LOG2E  1.4426950408889634f
#define LOG2E2 2.8853900817779268f

__device__ __forceinline__ float fast_rcp(float x) { return __builtin_amdgcn_rcpf(x); }
__device__ __forceinline__ float bcast_lane(float x, int lane) {
  return __int_as_float(__builtin_amdgcn_readlane(__float_as_int(x), lane));
}
__device__ __forceinline__ float max3f(float a, float b, float c) {
  return fmaxf(fmaxf(a, b), c);   // -> v_max3_f32
}
__device__ __forceinline__ float max14(const float s[NTAGS]) {
  float m0 = max3f(s[0], s[1], s[2]);
  float m1 = max3f(s[3], s[4], s[5]);
  float m2 = max3f(s[6], s[7], s[8]);
  float m3 = max3f(s[9], s[10], s[11]);
  float m4 = fmaxf(s[12], s[13]);
  return max3f(max3f(m0, m1, m2), m3, m4);
}
template<int CTRL>
__device__ __forceinline__ float quad_dpp(float x) {
  int xi = __float_as_int(x);
  int r = __builtin_amdgcn_update_dpp(xi, xi, CTRL, 0xF, 0xF, false);
  return __int_as_float(r);
}

// barrier that waits LDS only (lgkmcnt), NOT vmcnt -> global_load_lds stays in flight
__device__ __forceinline__ void lds_barrier() {
  __builtin_amdgcn_sched_barrier(0);
  asm volatile("s_waitcnt lgkmcnt(0)" ::: "memory");
  __builtin_amdgcn_s_barrier();
  __builtin_amdgcn_sched_barrier(0);
}

// async global->LDS, 16B per lane, vmcnt-only (never touches lgkmcnt)
__device__ __forceinline__ void gload_lds16(const float* gsrc, float* ldst) {
  __builtin_amdgcn_global_load_lds(
      (const __attribute__((address_space(1))) unsigned int*)gsrc,
      (__attribute__((address_space(3))) unsigned int*)ldst, 16, 0, 0);
}

// argmax over 14 values, first-index tie-break (matches jnp.argmax)
__device__ __forceinline__ void argmax14(const float s[NTAGS], float& bv, int& bi) {
#define MRG(va, ia, vb, ib, vo, io) { bool c_ = (vb) > (va); (vo) = c_ ? (vb) : (va); (io) = c_ ? (ib) : (ia); }
  float v0, v1, v2, v3, v4, v5, v6; int i0, i1, i2, i3, i4, i5, i6;
  MRG(s[0], 0, s[1], 1, v0, i0); MRG(s[2], 2, s[3], 3, v1, i1);
  MRG(s[4], 4, s[5], 5, v2, i2); MRG(s[6], 6, s[7], 7, v3, i3);
  MRG(s[8], 8, s[9], 9, v4, i4); MRG(s[10], 10, s[11], 11, v5, i5);
  MRG(s[12], 12, s[13], 13, v6, i6);
  float w0, w1, w2; int j0, j1, j2;
  MRG(v0, i0, v1, i1, w0, j0); MRG(v2, i2, v3, i3, w1, j1); MRG(v4, i4, v5, i5, w2, j2);
  float x0, x1; int y0, y1;
  MRG(w0, j0, w1, j1, x0, y0); MRG(w2, j2, v6, i6, x1, y1);
  MRG(x0, y0, x1, y1, bv, bi);
#undef MRG
}

// ---------------- prep: W transpose-pack (quad-permuted cols) + bias sums ----------------
__global__ void prep_k(const float* __restrict__ wihf, const float* __restrict__ wihb,
                       const float* __restrict__ bihf, const float* __restrict__ bhhf,
                       const float* __restrict__ bihb, const float* __restrict__ bhhb,
                       float* __restrict__ WT, float* __restrict__ bsum) {
  if (blockIdx.x < 1024) {
    int e = blockIdx.x * 256 + threadIdx.x;     // e over [EMBD*1024)
    int k = e >> 10, c = e & 1023;
    int cq = c & 511;
    int src = (cq & 3) * HD + (cq >> 2);
    WT[e] = (c < GATES) ? wihf[(size_t)src * EMBD + k] : wihb[(size_t)src * EMBD + k];
  } else {
    for (int i = 0; i < 4; ++i) {
      int c = threadIdx.x + i * 256;
      int cq = c & 511;
      int src = (cq & 3) * HD + (cq >> 2);
      bsum[c] = (c < GATES) ? (bihf[src] + bhhf[src]) : (bihb[src] + bhhb[src]);
    }
  }
}

// ---------------- embedding gather ----------------
__global__ void gather_k(const int* __restrict__ sent, const float* __restrict__ emb,
                         float* __restrict__ X) {
  int t = blockIdx.x;
  int row = sent[t];
  ((float4*)(X + (size_t)t * EMBD))[threadIdx.x] =
      ((const float4*)(emb + (size_t)row * EMBD))[threadIdx.x];
}

// ---------------- input-projection GEMM: G = X @ W^T + bsum ----------------
__global__ __launch_bounds__(256) void gemm_k(const float* __restrict__ X,
                                              const float* __restrict__ WT,
                                              const float* __restrict__ bsum,
                                              float* __restrict__ Gf, float* __restrict__ Gb) {
  __shared__ __align__(16) float As[32][68];   // [k][m], padded stride
  __shared__ __align__(16) float Bs[32][64];   // [k][n]
  const int tid = threadIdx.x;
  const int cb = blockIdx.x * 64;              // 0..960
  const int tb = blockIdx.y * 64;
  const bool flip = (cb >= GATES);
  const int ty = tid >> 4, tx = tid & 15;
  float acc[4][4] = {};

  const int r  = tid >> 2;                     // A-stage: row 0..63
  const int kq = (tid & 3) * 8;                // 8 k's
  const int kB = tid >> 3;                     // B-stage: k 0..31
  const int n8 = (tid & 7) * 8;

  const int trow = tb + r;
  const int src = flip ? (SEQ - 1 - trow) : trow;

  for (int k0 = 0; k0 < EMBD; k0 += 32) {
    const float* xp = X + (size_t)src * EMBD + k0 + kq;
    float4 xa = *(const float4*)xp;
    float4 xb = *(const float4*)(xp + 4);
    As[kq + 0][r] = xa.x; As[kq + 1][r] = xa.y; As[kq + 2][r] = xa.z; As[kq + 3][r] = xa.w;
    As[kq + 4][r] = xb.x; As[kq + 5][r] = xb.y; As[kq + 6][r] = xb.z; As[kq + 7][r] = xb.w;
    const float* wp = WT + (size_t)(k0 + kB) * 1024 + cb + n8;
    *(float4*)&Bs[kB][n8]     = *(const float4*)wp;
    *(float4*)&Bs[kB][n8 + 4] = *(const float4*)(wp + 4);
    __syncthreads();
    #pragma unroll
    for (int k = 0; k < 32; ++k) {
      float4 av = *(const float4*)&As[k][ty * 4];
      float4 bv = *(const float4*)&Bs[k][tx * 4];
      acc[0][0] = fmaf(av.x, bv.x, acc[0][0]); acc[0][1] = fmaf(av.x, bv.y, acc[0][1]);
      acc[0][2] = fmaf(av.x, bv.z, acc[0][2]); acc[0][3] = fmaf(av.x, bv.w, acc[0][3]);
      acc[1][0] = fmaf(av.y, bv.x, acc[1][0]); acc[1][1] = fmaf(av.y, bv.y, acc[1][1]);
      acc[1][2] = fmaf(av.y, bv.z, acc[1][2]); acc[1][3] = fmaf(av.y, bv.w, acc[1][3]);
      acc[2][0] = fmaf(av.z, bv.x, acc[2][0]); acc[2][1] = fmaf(av.z, bv.y, acc[2][1]);
      acc[2][2] = fmaf(av.z, bv.z, acc[2][2]); acc[2][3] = fmaf(av.z, bv.w, acc[2][3]);
      acc[3][0] = fmaf(av.w, bv.x, acc[3][0]); acc[3][1] = fmaf(av.w, bv.y, acc[3][1]);
      acc[3][2] = fmaf(av.w, bv.z, acc[3][2]); acc[3][3] = fmaf(av.w, bv.w, acc[3][3]);
    }
    __syncthreads();
  }
  float4 bz = *(const float4*)&bsum[cb + tx * 4];
  #pragma unroll
  for (int mm = 0; mm < 4; ++mm) {
    int t = tb + ty * 4 + mm;
    float4 v = { acc[mm][0] + bz.x, acc[mm][1] + bz.y, acc[mm][2] + bz.z, acc[mm][3] + bz.w };
    if (!flip) *(float4*)&Gf[(size_t)t * GATES + cb + tx * 4] = v;
    else       *(float4*)&Gb[(size_t)t * GATES + (cb - GATES) + tx * 4] = v;
  }
}

// ---------------- serial LSTM recurrence: 1 block per direction, 512 threads ----------------
// r4 structure (j=g>>2 hidden, q=g&3 k-quarter+own-gate, f16 packed matvec, DPP
// quad reduce/broadcast, ONE lds_barrier per step) with the per-step global ops
// REMOVED from the recurrence path:
//  - G staged 16 steps/group into LDS via global_load_lds (vmcnt-only, so the
//    per-step lgkmcnt(0) can never drain it); per-step G access = fast ds_read.
//  - h output buffered in an 8KB LDS ring, flushed once per group.
// One s_waitcnt vmcnt(0) per group boundary, always waiting on ops >=16 steps
// old -> effectively free.
__global__ __launch_bounds__(512, 2) void lstm_k(
    const float* __restrict__ whhf, const float* __restrict__ whhb,
    const float* __restrict__ Gf, const float* __restrict__ Gb,
    float* __restrict__ HF, float* __restrict__ HB) {
  const int dir = blockIdx.x;
  const float* __restrict__ G   = dir ? Gb : Gf;
  float* __restrict__ Hout      = dir ? HB : HF;
  const float* __restrict__ whh = dir ? whhb : whhf;
  const int g = threadIdx.x;
  const int j = g >> 2;         // hidden index 0..127
  const int q = g & 3;          // k-quarter AND own-gate index (i,f,g,o)
  const bool q0 = (q == 0);

  // weights: w2[gate][kk] = (W[gate*HD+j][q*32+2kk], W[..][q*32+2kk+1]) as half2
  __half2 w2[4][16];
  #pragma unroll
  for (int gi = 0; gi < 4; ++gi) {
    const float* wr = whh + (size_t)(gi * HD + j) * HD + q * 32;
    #pragma unroll
    for (int kk = 0; kk < 16; ++kk)
      w2[gi][kk] = __halves2half2(__float2half_rn(wr[2 * kk]),
                                  __float2half_rn(wr[2 * kk + 1]));
  }

  const float mm = (q == 2) ? -LOG2E2 : -LOG2E;
  const float aa = (q == 2) ? 2.0f : 1.0f;
  const float bb = (q == 2) ? -1.0f : 0.0f;

  constexpr int QS = 48;
  __shared__ __align__(16) __half hshA[4 * QS], hshB[4 * QS];
  __shared__ __align__(16) float Gs[2][GRP * GATES];   // 64 KB G staging, double-buffered
  __shared__ __align__(16) float ring[GRP][HD];        // 8 KB h ring
  if (g < 4 * QS) hshA[g] = __float2half_rn(0.0f);

  float cst = 0.0f;

  // stage group 'grp' of G (16 rows = 32 KB) into Gs[buf]: 4 chunks x 512 lanes x 16 B
  auto stage = [&](int buf, int grp) {
    const float* src = G + (size_t)grp * GRP * GATES + g * 4;
    float* dst = &Gs[buf][(g >> 6) * 256];   // wave-uniform base; HW adds lane*16B
    #pragma unroll
    for (int i = 0; i < 4; ++i)
      gload_lds16(src + i * 2048, dst + i * 2048);
  };

  stage(0, 0);
  stage(1, 1);
  asm volatile("s_waitcnt vmcnt(0)" ::: "memory");
  __builtin_amdgcn_sched_barrier(0);

  const int wslot = (j >> 5) * QS + (j & 31);
  const int rdoff = q * QS;

  // ring-flush constants: thread g moves one float4 of the group's h block
  const int fe  = g << 2;          // element 0..2044 within [16][HD]
  const int ftl = fe >> 7;         // local step 0..15
  const int fjj = fe & 127;

  lds_barrier();

  auto step = [&](const __half* hrd, __half* hwr, const float* gsl, float* ringrow) {
    float gcur = gsl[g];           // ds_read, conflict-free (2 lanes/bank)

    const float4* hq = (const float4*)(hrd + rdoff);
    float4 r0 = hq[0], r1 = hq[1], r2 = hq[2], r3 = hq[3];
    const __half2* h0 = (const __half2*)&r0;
    const __half2* h1 = (const __half2*)&r1;
    const __half2* h2 = (const __half2*)&r2;
    const __half2* h3 = (const __half2*)&r3;

    __half2 z2 = __float2half2_rn(0.0f);
    __half2 a0 = z2, a1 = z2, a2 = z2, a3 = z2;
    #pragma unroll
    for (int i = 0; i < 4; ++i) {
      a0 = __hfma2(w2[0][i], h0[i], a0);  a1 = __hfma2(w2[1][i], h0[i], a1);
      a2 = __hfma2(w2[2][i], h0[i], a2);  a3 = __hfma2(w2[3][i], h0[i], a3);
      a0 = __hfma2(w2[0][4 + i], h1[i], a0);  a1 = __hfma2(w2[1][4 + i], h1[i], a1);
      a2 = __hfma2(w2[2][4 + i], h1[i], a2);  a3 = __hfma2(w2[3][4 + i], h1[i], a3);
      a0 = __hfma2(w2[0][8 + i], h2[i], a0);  a1 = __hfma2(w2[1][8 + i], h2[i], a1);
      a2 = __hfma2(w2[2][8 + i], h2[i], a2);  a3 = __hfma2(w2[3][8 + i], h2[i], a3);
      a0 = __hfma2(w2[0][12 + i], h3[i], a0); a1 = __hfma2(w2[1][12 + i], h3[i], a1);
      a2 = __hfma2(w2[2][12 + i], h3[i], a2); a3 = __hfma2(w2[3][12 + i], h3[i], a3);
    }
    float p0 = __low2float(a0) + __high2float(a0);
    float p1 = __low2float(a1) + __high2float(a1);
    float p2 = __low2float(a2) + __high2float(a2);
    float p3 = __low2float(a3) + __high2float(a3);

    // quad butterfly all-reduce
    p0 += quad_dpp<0xB1>(p0); p1 += quad_dpp<0xB1>(p1);
    p2 += quad_dpp<0xB1>(p2); p3 += quad_dpp<0xB1>(p3);
    p0 += quad_dpp<0x4E>(p0); p1 += quad_dpp<0x4E>(p1);
    p2 += quad_dpp<0x4E>(p2); p3 += quad_dpp<0x4E>(p3);

    float t0 = (q & 1) ? p1 : p0;
    float t1 = (q & 1) ? p3 : p2;
    float pre = ((q & 2) ? t1 : t0) + gcur;
    float act = fmaf(aa, fast_rcp(1.0f + exp2f(pre * mm)), bb);

    float i_ = quad_dpp<0x00>(act);
    float f_ = quad_dpp<0x55>(act);
    float g_ = quad_dpp<0xAA>(act);
    float o_ = quad_dpp<0xFF>(act);
    cst = fmaf(f_, cst, i_ * g_);
    float th = fmaf(2.0f, fast_rcp(1.0f + exp2f(cst * -LOG2E2)), -1.0f);
    float hj = o_ * th;
    if (q0) { hwr[wslot] = __float2half_rn(hj); ringrow[j] = hj; }
    lds_barrier();   // the ONLY barrier per step (lgkmcnt-only)
  };

  for (int grp = 0; grp < SEQ / GRP; ++grp) {
    const float* Gbuf = Gs[grp & 1];
    #pragma unroll
    for (int u = 0; u < GRP / 2; ++u) {
      step(hshA, hshB, Gbuf + (2 * u) * GATES,     &ring[2 * u][0]);
      step(hshB, hshA, Gbuf + (2 * u + 1) * GATES, &ring[2 * u + 1][0]);
    }
    // group boundary: everything outstanding in vmcnt is >=16 steps old -> free
    asm volatile("s_waitcnt vmcnt(0)" ::: "memory");
    __builtin_amdgcn_sched_barrier(0);
    // flush h ring (visible after last step's barrier)
    {
      float4 v = *(const float4*)(&ring[0][0] + fe);
      int t = grp * GRP + ftl;
      size_t row = dir ? (size_t)(SEQ - 1 - t) : (size_t)t;
      *(float4*)(Hout + row * HD + fjj) = v;
    }
    if (grp + 2 < SEQ / GRP) stage(grp & 1, grp + 2);
    lds_barrier();   // protects ring (flush reads done) before next group rewrites
  }
}

// ---------------- tag-space projection: feats = [hf|hb] @ w_tag^T + b_tag ----------------
__global__ void feats_k(const float* __restrict__ HF, const float* __restrict__ HB,
                        const float* __restrict__ wtag, const float* __restrict__ btag,
                        float* __restrict__ feats) {
  const int t = blockIdx.x, l = threadIdx.x;   // 64 lanes
  float2 a = ((const float2*)(HF + (size_t)t * HD))[l];
  float2 b = ((const float2*)(HB + (size_t)t * HD))[l];
  float p[NTAGS];
  #pragma unroll
  for (int n = 0; n < NTAGS; ++n) {
    const float* wr = wtag + (size_t)n * 256;
    float2 w0 = ((const float2*)wr)[l];
    float2 w1 = ((const float2*)(wr + HD))[l];
    p[n] = a.x * w0.x + a.y * w0.y + b.x * w1.x + b.y * w1.y;
  }
  #pragma unroll
  for (int n = 0; n < NTAGS; ++n) {
    float v = p[n];
    for (int off = 32; off > 0; off >>= 1) v += __shfl_down(v, off);
    if (l == 0) feats[(size_t)t * 16 + n] = v + btag[n];
  }
}

// ---------------- Viterbi, parallel-scan formulation (unchanged, measured 308us total) ----
__global__ __launch_bounds__(256) void vit_a(const float* __restrict__ feats,
                                             const float* __restrict__ trans,
                                             float* __restrict__ Ac) {
  const int c = blockIdx.x;
  const int tid = threadIdx.x;
  const int n = tid % NTAGS, p = tid / NTAGS;
  const bool act = tid < NTAGS * NTAGS;
  __shared__ __align__(16) float fl[128][16];   // chunk feats
  __shared__ float Ab[2][NTAGS][17];            // stride-17: conflict-light

  const float4* fsrc = (const float4*)(feats + (size_t)c * 128 * 16);
  #pragma unroll
  for (int i = 0; i < 2; ++i)
    ((float4*)&fl[0][0])[tid + i * 256] = fsrc[tid + i * 256];

  float Tr[NTAGS];
  if (act) {
    #pragma unroll
    for (int qq = 0; qq < NTAGS; ++qq) Tr[qq] = trans[n * NTAGS + qq];
  }
  __syncthreads();
  if (act) Ab[0][n][p] = Tr[p] + fl[0][n];      // first step: A = M_{t0}
  __syncthreads();

  int cur = 0;
  for (int tl = 1; tl < 128; ++tl) {
    if (act) {
      float s[NTAGS];
      #pragma unroll
      for (int qq = 0; qq < NTAGS; ++qq) s[qq] = Tr[qq] + Ab[cur][qq][p];
      Ab[cur ^ 1][n][p] = max14(s) + fl[tl][n];
    }
    __syncthreads();
    cur ^= 1;
  }
  if (act) Ac[(size_t)c * 256 + n * 16 + p] = Ab[cur][n][p];
}

__global__ void vit_b(const float* __restrict__ trans, const float* __restrict__ Ac,
                      float* __restrict__ fvb, float* __restrict__ out,
                      float* __restrict__ sb) {
  const int n = threadIdx.x;
  const bool act = n < NTAGS;
  float fv = (n == TAG_START) ? 0.0f : NEGV;
  for (int c = 0; c < 64; ++c) {
    if (act) fvb[c * 16 + n] = fv;
    float Ar[NTAGS];
    #pragma unroll
    for (int p = 0; p < NTAGS; ++p) Ar[p] = act ? Ac[(size_t)c * 256 + n * 16 + p] : NEGV;
    float s[NTAGS];
    #pragma unroll
    for (int p = 0; p < NTAGS; ++p) s[p] = Ar[p] + bcast_lane(fv, p);
    float nf = max14(s);
    fv = act ? nf : NEGV;
  }
  float tn = fv + (act ? trans[TAG_STOP * NTAGS + n] : NEGV);
  float tv[NTAGS];
  #pragma unroll
  for (int p = 0; p < NTAGS; ++p) tv[p] = bcast_lane(tn, p);
  if (n == 0) {
    float bv; int bi;
    argmax14(tv, bv, bi);
    out[0] = bv;                       // score
    ((int*)sb)[0] = bi;                // best terminal tag
  }
}

__global__ void vit_c(const float* __restrict__ feats, const float* __restrict__ trans,
                      const float* __restrict__ fvb, unsigned char* __restrict__ bpg) {
  const int c = blockIdx.x;
  const int n = threadIdx.x;
  const bool act = n < NTAGS;
  float Tn[NTAGS];
  #pragma unroll
  for (int p = 0; p < NTAGS; ++p) Tn[p] = act ? trans[n * NTAGS + p] : 0.0f;
  float fv = act ? fvb[c * 16 + n] : NEGV;
  const int t0 = c * 128;

  float fbuf[8];
  #pragma unroll
  for (int u = 0; u < 8; ++u) fbuf[u] = act ? feats[(size_t)(t0 + u) * 16 + n] : 0.0f;

  for (int tb = 0; tb < 128; tb += 8) {
    #pragma unroll
    for (int u = 0; u < 8; ++u) {
      const int t = t0 + tb + u;
      float ftc = fbuf[u];
      fbuf[u] = act ? feats[(size_t)(t + 8) * 16 + n] : 0.0f;   // padded rows
      float s[NTAGS];
      #pragma unroll
      for (int p = 0; p < NTAGS; ++p) s[p] = bcast_lane(fv, p) + Tn[p];
      float bv = max14(s);
      fv = bv + ftc;
      int bi = 13;
      #pragma unroll
      for (int p = 12; p >= 0; --p) bi = (s[p] == bv) ? p : bi;
      if (act) bpg[(size_t)t * 16 + n] = (unsigned char)bi;
    }
  }
}

__global__ __launch_bounds__(1024) void vit_d(const unsigned char* __restrict__ bpg,
                                              const float* __restrict__ sb,
                                              float* __restrict__ out) {
  __shared__ int sh_M[64 * 16];
  __shared__ int sh_B[64];
  const int tid = threadIdx.x;
  {                               // phase B: compose 128-step backpointer maps per chunk
    const int c = tid >> 4, k = tid & 15;
    if (c >= 1 && c < 64 && k < NTAGS) {
      int x = k;
      for (int i = 127; i >= 0; --i) x = bpg[((size_t)(c * 128 + i)) * 16 + x];
      sh_M[c * 16 + k] = x;
    }
  }
  __syncthreads();
  if (tid == 0) {                 // phase C: serial walk over 64 chunk boundaries
    int b = ((const int*)sb)[0];
    sh_B[63] = b;
    for (int c = 63; c >= 1; --c) { b = sh_M[c * 16 + b]; sh_B[c - 1] = b; }
  }
  __syncthreads();
  if (tid < 64) {                 // phase D: chunks re-walk in parallel, emit path
    const int c = tid;
    int x = sh_B[c];
    out[1 + c * 128 + 127] = (float)x;
    for (int i = 127; i >= 1; --i) {
      x = bpg[((size_t)(c * 128 + i)) * 16 + x];
      out[1 + c * 128 + i - 1] = (float)x;
    }
  }
}

extern "C" void kernel_launch(void* const* d_in, const int* in_sizes, int n_in,
                              void* d_out, int out_size, void* d_ws, size_t ws_size,
                              hipStream_t stream) {
  (void)in_sizes; (void)n_in; (void)out_size; (void)ws_size;
  const int*   sent = (const int*)d_in[0];
  const float* emb  = (const float*)d_in[1];
  const float* wihf = (const float*)d_in[2];
  const float* whhf = (const float*)d_in[3];
  const float* bihf = (const float*)d_in[4];
  const float* bhhf = (const float*)d_in[5];
  const float* wihb = (const float*)d_in[6];
  const float* whhb = (const float*)d_in[7];
  const float* bihb = (const float*)d_in[8];
  const float* bhhb = (const float*)d_in[9];
  const float* wtag = (const float*)d_in[10];
  const float* btag = (const float*)d_in[11];
  const float* trans = (const float*)d_in[12];

  float* ws = (float*)d_ws;
  float* X    = ws + OFF_X;
  float* WT   = ws + OFF_WT;
  float* BS   = ws + OFF_BSUM;
  float* Gf   = ws + OFF_GF;
  float* Gb   = ws + OFF_GB;
  float* HF   = ws + OFF_HF;
  float* HB   = ws + OFF_HB;
  float* FE   = ws + OFF_FEATS;
  unsigned char* bpg = (unsigned char*)(ws + OFF_BP);
  float* AC   = ws + OFF_AC;
  float* FVB  = ws + OFF_FVB;
  float* SB   = ws + OFF_SB;
  float* out = (float*)d_out;

  prep_k<<<1025, 256, 0, stream>>>(wihf, wihb, bihf, bhhf, bihb, bhhb, WT, BS);
  gather_k<<<SEQ, 64, 0, stream>>>(sent, emb, X);
  gemm_k<<<dim3(16, 128), 256, 0, stream>>>(X, WT, BS, Gf, Gb);
  lstm_k<<<2, 512, 0, stream>>>(whhf, whhb, Gf, Gb, HF, HB);
  feats_k<<<SEQ, 64, 0, stream>>>(HF, HB, wtag, btag, FE);
  vit_a<<<64, 256, 0, stream>>>(FE, trans, AC);
  vit_b<<<1, 64, 0, stream>>>(trans, AC, FVB, out, SB);
  vit_c<<<64, 64, 0, stream>>>(FE, trans, FVB, bpg);
  vit_d<<<1, 1024, 0, stream>>>(bpg, SB, out);
}

// Round 9
// 4739.991 us; speedup vs baseline: 1.9729x; 1.1827x over previous
//
#include <hip/hip_runtime.h>
#include <hip/hip_fp16.h>
#include <math.h>

#define SEQ    8192
#define EMBD   256
#define HD     128
#define GATES  512
#define NTAGS  14
#define TAG_START 12
#define TAG_STOP  13
#define NEGV   (-10000.0f)

// ---- ws layout (float offsets) ----
static constexpr size_t OFF_X     = 0;                               // [SEQ][EMBD]
static constexpr size_t OFF_WT    = OFF_X + (size_t)SEQ * EMBD;      // [EMBD][1024]
static constexpr size_t OFF_BSUM  = OFF_WT + (size_t)EMBD * 1024;    // [1024]
static constexpr size_t OFF_GF    = OFF_BSUM + 1024;                 // [SEQ+4][GATES] quad-layout
static constexpr size_t OFF_GB    = OFF_GF + (size_t)(SEQ + 4) * GATES;
static constexpr size_t OFF_HF    = OFF_GB + (size_t)(SEQ + 4) * GATES; // [SEQ][HD]
static constexpr size_t OFF_HB    = OFF_HF + (size_t)SEQ * HD;          // [SEQ][HD]
static constexpr size_t OFF_FEATS = OFF_HB + (size_t)SEQ * HD;          // [SEQ+8][16]
static constexpr size_t OFF_BP    = OFF_FEATS + (size_t)(SEQ + 8) * 16; // uchar[SEQ][16]
static constexpr size_t OFF_AC    = OFF_BP + (size_t)SEQ * 16 / 4;      // [64][256] chunk matrices
static constexpr size_t OFF_FVB   = OFF_AC + (size_t)64 * 256;          // [64][16] boundary fv
static constexpr size_t OFF_SB    = OFF_FVB + 1024;                     // [4] best-tag etc.

#define LOG2E  1.4426950408889634f
#define LOG2E2 2.8853900817779268f

typedef _Float16 half2_t __attribute__((ext_vector_type(2)));

__device__ __forceinline__ float fast_rcp(float x) { return __builtin_amdgcn_rcpf(x); }
__device__ __forceinline__ float bcast_lane(float x, int lane) {
  return __int_as_float(__builtin_amdgcn_readlane(__float_as_int(x), lane));
}
__device__ __forceinline__ float max3f(float a, float b, float c) {
  return fmaxf(fmaxf(a, b), c);   // -> v_max3_f32
}
__device__ __forceinline__ float max14(const float s[NTAGS]) {
  float m0 = max3f(s[0], s[1], s[2]);
  float m1 = max3f(s[3], s[4], s[5]);
  float m2 = max3f(s[6], s[7], s[8]);
  float m3 = max3f(s[9], s[10], s[11]);
  float m4 = fmaxf(s[12], s[13]);
  return max3f(max3f(m0, m1, m2), m3, m4);
}
template<int CTRL>
__device__ __forceinline__ float quad_dpp(float x) {
  int xi = __float_as_int(x);
  int r = __builtin_amdgcn_update_dpp(xi, xi, CTRL, 0xF, 0xF, false);
  return __int_as_float(r);
}

// f32-accumulating f16 dot2 (v_dot2_f32_f16) with safe fallback
__device__ __forceinline__ float dot2acc(half2_t a, half2_t b, float c) {
#if __has_builtin(__builtin_amdgcn_fdot2)
  return __builtin_amdgcn_fdot2(a, b, c, false);
#else
  return fmaf((float)a[0], (float)b[0], fmaf((float)a[1], (float)b[1], c));
#endif
}

// sigmoid / tanh via native exp2+rcp (passed absmax=0 in r4..r8)
__device__ __forceinline__ float sigf(float x) {
  return fast_rcp(1.0f + exp2f(x * -LOG2E));
}
__device__ __forceinline__ float tanhf_(float x) {
  return fmaf(2.0f, fast_rcp(1.0f + exp2f(x * -LOG2E2)), -1.0f);
}

// barrier that waits LDS only (lgkmcnt), NOT vmcnt -> global prefetch stays in flight
__device__ __forceinline__ void lds_barrier() {
  __builtin_amdgcn_sched_barrier(0);
  asm volatile("s_waitcnt lgkmcnt(0)" ::: "memory");
  __builtin_amdgcn_s_barrier();
  __builtin_amdgcn_sched_barrier(0);
}

// argmax over 14 values, first-index tie-break (matches jnp.argmax)
__device__ __forceinline__ void argmax14(const float s[NTAGS], float& bv, int& bi) {
#define MRG(va, ia, vb, ib, vo, io) { bool c_ = (vb) > (va); (vo) = c_ ? (vb) : (va); (io) = c_ ? (ib) : (ia); }
  float v0, v1, v2, v3, v4, v5, v6; int i0, i1, i2, i3, i4, i5, i6;
  MRG(s[0], 0, s[1], 1, v0, i0); MRG(s[2], 2, s[3], 3, v1, i1);
  MRG(s[4], 4, s[5], 5, v2, i2); MRG(s[6], 6, s[7], 7, v3, i3);
  MRG(s[8], 8, s[9], 9, v4, i4); MRG(s[10], 10, s[11], 11, v5, i5);
  MRG(s[12], 12, s[13], 13, v6, i6);
  float w0, w1, w2; int j0, j1, j2;
  MRG(v0, i0, v1, i1, w0, j0); MRG(v2, i2, v3, i3, w1, j1); MRG(v4, i4, v5, i5, w2, j2);
  float x0, x1; int y0, y1;
  MRG(w0, j0, w1, j1, x0, y0); MRG(w2, j2, v6, i6, x1, y1);
  MRG(x0, y0, x1, y1, bv, bi);
#undef MRG
}

// ---------------- prep: W transpose-pack (quad-permuted cols) + bias sums ----------------
__global__ void prep_k(const float* __restrict__ wihf, const float* __restrict__ wihb,
                       const float* __restrict__ bihf, const float* __restrict__ bhhf,
                       const float* __restrict__ bihb, const float* __restrict__ bhhb,
                       float* __restrict__ WT, float* __restrict__ bsum) {
  if (blockIdx.x < 1024) {
    int e = blockIdx.x * 256 + threadIdx.x;     // e over [EMBD*1024)
    int k = e >> 10, c = e & 1023;
    int cq = c & 511;
    int src = (cq & 3) * HD + (cq >> 2);
    WT[e] = (c < GATES) ? wihf[(size_t)src * EMBD + k] : wihb[(size_t)src * EMBD + k];
  } else {
    for (int i = 0; i < 4; ++i) {
      int c = threadIdx.x + i * 256;
      int cq = c & 511;
      int src = (cq & 3) * HD + (cq >> 2);
      bsum[c] = (c < GATES) ? (bihf[src] + bhhf[src]) : (bihb[src] + bhhb[src]);
    }
  }
}

// ---------------- embedding gather ----------------
__global__ void gather_k(const int* __restrict__ sent, const float* __restrict__ emb,
                         float* __restrict__ X) {
  int t = blockIdx.x;
  int row = sent[t];
  ((float4*)(X + (size_t)t * EMBD))[threadIdx.x] =
      ((const float4*)(emb + (size_t)row * EMBD))[threadIdx.x];
}

// ---------------- input-projection GEMM: G = X @ W^T + bsum ----------------
__global__ __launch_bounds__(256) void gemm_k(const float* __restrict__ X,
                                              const float* __restrict__ WT,
                                              const float* __restrict__ bsum,
                                              float* __restrict__ Gf, float* __restrict__ Gb) {
  __shared__ __align__(16) float As[32][68];   // [k][m], padded stride
  __shared__ __align__(16) float Bs[32][64];   // [k][n]
  const int tid = threadIdx.x;
  const int cb = blockIdx.x * 64;              // 0..960
  const int tb = blockIdx.y * 64;
  const bool flip = (cb >= GATES);
  const int ty = tid >> 4, tx = tid & 15;
  float acc[4][4] = {};

  const int r  = tid >> 2;                     // A-stage: row 0..63
  const int kq = (tid & 3) * 8;                // 8 k's
  const int kB = tid >> 3;                     // B-stage: k 0..31
  const int n8 = (tid & 7) * 8;

  const int trow = tb + r;
  const int src = flip ? (SEQ - 1 - trow) : trow;

  for (int k0 = 0; k0 < EMBD; k0 += 32) {
    const float* xp = X + (size_t)src * EMBD + k0 + kq;
    float4 xa = *(const float4*)xp;
    float4 xb = *(const float4*)(xp + 4);
    As[kq + 0][r] = xa.x; As[kq + 1][r] = xa.y; As[kq + 2][r] = xa.z; As[kq + 3][r] = xa.w;
    As[kq + 4][r] = xb.x; As[kq + 5][r] = xb.y; As[kq + 6][r] = xb.z; As[kq + 7][r] = xb.w;
    const float* wp = WT + (size_t)(k0 + kB) * 1024 + cb + n8;
    *(float4*)&Bs[kB][n8]     = *(const float4*)wp;
    *(float4*)&Bs[kB][n8 + 4] = *(const float4*)(wp + 4);
    __syncthreads();
    #pragma unroll
    for (int k = 0; k < 32; ++k) {
      float4 av = *(const float4*)&As[k][ty * 4];
      float4 bv = *(const float4*)&Bs[k][tx * 4];
      acc[0][0] = fmaf(av.x, bv.x, acc[0][0]); acc[0][1] = fmaf(av.x, bv.y, acc[0][1]);
      acc[0][2] = fmaf(av.x, bv.z, acc[0][2]); acc[0][3] = fmaf(av.x, bv.w, acc[0][3]);
      acc[1][0] = fmaf(av.y, bv.x, acc[1][0]); acc[1][1] = fmaf(av.y, bv.y, acc[1][1]);
      acc[1][2] = fmaf(av.y, bv.z, acc[1][2]); acc[1][3] = fmaf(av.y, bv.w, acc[1][3]);
      acc[2][0] = fmaf(av.z, bv.x, acc[2][0]); acc[2][1] = fmaf(av.z, bv.y, acc[2][1]);
      acc[2][2] = fmaf(av.z, bv.z, acc[2][2]); acc[2][3] = fmaf(av.z, bv.w, acc[2][3]);
      acc[3][0] = fmaf(av.w, bv.x, acc[3][0]); acc[3][1] = fmaf(av.w, bv.y, acc[3][1]);
      acc[3][2] = fmaf(av.w, bv.z, acc[3][2]); acc[3][3] = fmaf(av.w, bv.w, acc[3][3]);
    }
    __syncthreads();
  }
  float4 bz = *(const float4*)&bsum[cb + tx * 4];
  #pragma unroll
  for (int mm = 0; mm < 4; ++mm) {
    int t = tb + ty * 4 + mm;
    float4 v = { acc[mm][0] + bz.x, acc[mm][1] + bz.y, acc[mm][2] + bz.z, acc[mm][3] + bz.w };
    if (!flip) *(float4*)&Gf[(size_t)t * GATES + cb + tx * 4] = v;
    else       *(float4*)&Gb[(size_t)t * GATES + (cb - GATES) + tx * 4] = v;
  }
}

// ---------------- serial LSTM recurrence: 1 block per direction, 256 threads ----------------
// Thread t: hidden j = t>>1, k-half s = t&1. Each thread computes ALL FOUR gate
// partial dot-products of its j over k in [64s, 64s+64) via v_dot2_f32_f16
// (f32 accumulate, no f16 pack step). Reduce = ONE DPP xor1 round (4 ops, no
// select, no broadcast); every lane then computes all 4 activations + cell
// update locally (pair-redundant, deterministic). 4 waves -> cheaper barrier
// than 8. G = one coalesced float4/step, depth-2 register prefetch. One
// lgkmcnt-only barrier per step; h double-buffered in LDS (f16).
__global__ __launch_bounds__(256, 1) void lstm_k(
    const float* __restrict__ whhf, const float* __restrict__ whhb,
    const float* __restrict__ Gf, const float* __restrict__ Gb,
    float* __restrict__ HF, float* __restrict__ HB) {
  const int dir = blockIdx.x;
  const float* __restrict__ G   = dir ? Gb : Gf;
  float* __restrict__ Hout      = dir ? HB : HF;
  const float* __restrict__ whh = dir ? whhb : whhf;
  const int tt = threadIdx.x;
  const int j = tt >> 1;        // hidden index 0..127
  const int s = tt & 1;         // k-half 0..1
  const bool s0 = (s == 0);

  // weights: w2[gate][kk] covers k-half [64s, 64s+64) of row (gate*HD + j)
  half2_t w2[4][32];
  #pragma unroll
  for (int gi = 0; gi < 4; ++gi) {
    const float* wr = whh + (size_t)(gi * HD + j) * HD + s * 64;
    #pragma unroll
    for (int kk = 0; kk < 32; ++kk) {
      half2_t w; w[0] = (_Float16)wr[2 * kk]; w[1] = (_Float16)wr[2 * kk + 1];
      w2[gi][kk] = w;
    }
  }

  __shared__ __align__(16) __half hA[HD], hB[HD];
  if (tt < HD) hA[tt] = __float2half_rn(0.0f);
  float cst = 0.0f;

  // depth-2 float4 G prefetch: gA serves even rows, gB odd rows
  const float* gpA = G + 4 * j;
  const float* gpB = G + GATES + 4 * j;
  float4 gA = *(const float4*)gpA; gpA += 2 * GATES;
  float4 gB = *(const float4*)gpB; gpB += 2 * GATES;

  float* hout = Hout + (size_t)(dir ? (SEQ - 1) : 0) * HD + j;
  const ptrdiff_t hstep = dir ? -(ptrdiff_t)HD : (ptrdiff_t)HD;

  lds_barrier();

  auto step = [&](const __half* hrd, __half* hwr, float4& gslot, const float*& gptr) {
    float4 gcur = gslot;
    gslot = *(const float4*)gptr;   // row t+2, lands ~2 steps later
    gptr += 2 * GATES;

    // my k-half of h: 64 halfs = 8 x b128 (2 distinct bcast addrs/instr, conflict-free)
    const float4* hp = (const float4*)(hrd + (s << 6));
    float a[4][2] = {};
    #pragma unroll
    for (int i = 0; i < 8; ++i) {
      float4 hv = hp[i];
      const half2_t* hh = (const half2_t*)&hv;   // 4 half2
      #pragma unroll
      for (int m = 0; m < 4; ++m) {
        const int kk = i * 4 + m;
        a[0][kk & 1] = dot2acc(w2[0][kk], hh[m], a[0][kk & 1]);
        a[1][kk & 1] = dot2acc(w2[1][kk], hh[m], a[1][kk & 1]);
        a[2][kk & 1] = dot2acc(w2[2][kk], hh[m], a[2][kk & 1]);
        a[3][kk & 1] = dot2acc(w2[3][kk], hh[m], a[3][kk & 1]);
      }
    }
    float p0 = a[0][0] + a[0][1];
    float p1 = a[1][0] + a[1][1];
    float p2 = a[2][0] + a[2][1];
    float p3 = a[3][0] + a[3][1];

    // single DPP xor1 round completes all 4 sums in both pair lanes
    p0 += quad_dpp<0xB1>(p0);
    p1 += quad_dpp<0xB1>(p1);
    p2 += quad_dpp<0xB1>(p2);
    p3 += quad_dpp<0xB1>(p3);

    float i_ = sigf(p0 + gcur.x);
    float f_ = sigf(p1 + gcur.y);
    float g_ = tanhf_(p2 + gcur.z);
    float o_ = sigf(p3 + gcur.w);
    cst = fmaf(f_, cst, i_ * g_);
    float hj = o_ * tanhf_(cst);
    if (s0) { hwr[j] = __float2half_rn(hj); *hout = hj; }   // fire-and-forget store
    hout += hstep;
    lds_barrier();   // the ONLY barrier per step (lgkmcnt-only)
  };

  for (int t = 0; t < SEQ; t += 2) {
    step(hA, hB, gA, gpA);
    step(hB, hA, gB, gpB);
  }
}

// ---------------- tag-space projection: feats = [hf|hb] @ w_tag^T + b_tag ----------------
__global__ void feats_k(const float* __restrict__ HF, const float* __restrict__ HB,
                        const float* __restrict__ wtag, const float* __restrict__ btag,
                        float* __restrict__ feats) {
  const int t = blockIdx.x, l = threadIdx.x;   // 64 lanes
  float2 a = ((const float2*)(HF + (size_t)t * HD))[l];
  float2 b = ((const float2*)(HB + (size_t)t * HD))[l];
  float p[NTAGS];
  #pragma unroll
  for (int n = 0; n < NTAGS; ++n) {
    const float* wr = wtag + (size_t)n * 256;
    float2 w0 = ((const float2*)wr)[l];
    float2 w1 = ((const float2*)(wr + HD))[l];
    p[n] = a.x * w0.x + a.y * w0.y + b.x * w1.x + b.y * w1.y;
  }
  #pragma unroll
  for (int n = 0; n < NTAGS; ++n) {
    float v = p[n];
    for (int off = 32; off > 0; off >>= 1) v += __shfl_down(v, off);
    if (l == 0) feats[(size_t)t * 16 + n] = v + btag[n];
  }
}

// ---------------- Viterbi, parallel-scan formulation (measured ~300us total) ----------
__global__ __launch_bounds__(256) void vit_a(const float* __restrict__ feats,
                                             const float* __restrict__ trans,
                                             float* __restrict__ Ac) {
  const int c = blockIdx.x;
  const int tid = threadIdx.x;
  const int n = tid % NTAGS, p = tid / NTAGS;
  const bool act = tid < NTAGS * NTAGS;
  __shared__ __align__(16) float fl[128][16];   // chunk feats
  __shared__ float Ab[2][NTAGS][17];            // stride-17: conflict-light

  const float4* fsrc = (const float4*)(feats + (size_t)c * 128 * 16);
  #pragma unroll
  for (int i = 0; i < 2; ++i)
    ((float4*)&fl[0][0])[tid + i * 256] = fsrc[tid + i * 256];

  float Tr[NTAGS];
  if (act) {
    #pragma unroll
    for (int qq = 0; qq < NTAGS; ++qq) Tr[qq] = trans[n * NTAGS + qq];
  }
  __syncthreads();
  if (act) Ab[0][n][p] = Tr[p] + fl[0][n];      // first step: A = M_{t0}
  __syncthreads();

  int cur = 0;
  for (int tl = 1; tl < 128; ++tl) {
    if (act) {
      float s[NTAGS];
      #pragma unroll
      for (int qq = 0; qq < NTAGS; ++qq) s[qq] = Tr[qq] + Ab[cur][qq][p];
      Ab[cur ^ 1][n][p] = max14(s) + fl[tl][n];
    }
    __syncthreads();
    cur ^= 1;
  }
  if (act) Ac[(size_t)c * 256 + n * 16 + p] = Ab[cur][n][p];
}

__global__ void vit_b(const float* __restrict__ trans, const float* __restrict__ Ac,
                      float* __restrict__ fvb, float* __restrict__ out,
                      float* __restrict__ sb) {
  const int n = threadIdx.x;
  const bool act = n < NTAGS;
  float fv = (n == TAG_START) ? 0.0f : NEGV;
  for (int c = 0; c < 64; ++c) {
    if (act) fvb[c * 16 + n] = fv;
    float Ar[NTAGS];
    #pragma unroll
    for (int p = 0; p < NTAGS; ++p) Ar[p] = act ? Ac[(size_t)c * 256 + n * 16 + p] : NEGV;
    float s[NTAGS];
    #pragma unroll
    for (int p = 0; p < NTAGS; ++p) s[p] = Ar[p] + bcast_lane(fv, p);
    float nf = max14(s);
    fv = act ? nf : NEGV;
  }
  float tn = fv + (act ? trans[TAG_STOP * NTAGS + n] : NEGV);
  float tv[NTAGS];
  #pragma unroll
  for (int p = 0; p < NTAGS; ++p) tv[p] = bcast_lane(tn, p);
  if (n == 0) {
    float bv; int bi;
    argmax14(tv, bv, bi);
    out[0] = bv;                       // score
    ((int*)sb)[0] = bi;                // best terminal tag
  }
}

__global__ void vit_c(const float* __restrict__ feats, const float* __restrict__ trans,
                      const float* __restrict__ fvb, unsigned char* __restrict__ bpg) {
  const int c = blockIdx.x;
  const int n = threadIdx.x;
  const bool act = n < NTAGS;
  float Tn[NTAGS];
  #pragma unroll
  for (int p = 0; p < NTAGS; ++p) Tn[p] = act ? trans[n * NTAGS + p] : 0.0f;
  float fv = act ? fvb[c * 16 + n] : NEGV;
  const int t0 = c * 128;

  float fbuf[8];
  #pragma unroll
  for (int u = 0; u < 8; ++u) fbuf[u] = act ? feats[(size_t)(t0 + u) * 16 + n] : 0.0f;

  for (int tb = 0; tb < 128; tb += 8) {
    #pragma unroll
    for (int u = 0; u < 8; ++u) {
      const int t = t0 + tb + u;
      float ftc = fbuf[u];
      fbuf[u] = act ? feats[(size_t)(t + 8) * 16 + n] : 0.0f;   // padded rows
      float s[NTAGS];
      #pragma unroll
      for (int p = 0; p < NTAGS; ++p) s[p] = bcast_lane(fv, p) + Tn[p];
      float bv = max14(s);
      fv = bv + ftc;
      int bi = 13;
      #pragma unroll
      for (int p = 12; p >= 0; --p) bi = (s[p] == bv) ? p : bi;
      if (act) bpg[(size_t)t * 16 + n] = (unsigned char)bi;
    }
  }
}

__global__ __launch_bounds__(1024) void vit_d(const unsigned char* __restrict__ bpg,
                                              const float* __restrict__ sb,
                                              float* __restrict__ out) {
  __shared__ int sh_M[64 * 16];
  __shared__ int sh_B[64];
  const int tid = threadIdx.x;
  {                               // phase B: compose 128-step backpointer maps per chunk
    const int c = tid >> 4, k = tid & 15;
    if (c >= 1 && c < 64 && k < NTAGS) {
      int x = k;
      for (int i = 127; i >= 0; --i) x = bpg[((size_t)(c * 128 + i)) * 16 + x];
      sh_M[c * 16 + k] = x;
    }
  }
  __syncthreads();
  if (tid == 0) {                 // phase C: serial walk over 64 chunk boundaries
    int b = ((const int*)sb)[0];
    sh_B[63] = b;
    for (int c = 63; c >= 1; --c) { b = sh_M[c * 16 + b]; sh_B[c - 1] = b; }
  }
  __syncthreads();
  if (tid < 64) {                 // phase D: chunks re-walk in parallel, emit path
    const int c = tid;
    int x = sh_B[c];
    out[1 + c * 128 + 127] = (float)x;
    for (int i = 127; i >= 1; --i) {
      x = bpg[((size_t)(c * 128 + i)) * 16 + x];
      out[1 + c * 128 + i - 1] = (float)x;
    }
  }
}

extern "C" void kernel_launch(void* const* d_in, const int* in_sizes, int n_in,
                              void* d_out, int out_size, void* d_ws, size_t ws_size,
                              hipStream_t stream) {
  (void)in_sizes; (void)n_in; (void)out_size; (void)ws_size;
  const int*   sent = (const int*)d_in[0];
  const float* emb  = (const float*)d_in[1];
  const float* wihf = (const float*)d_in[2];
  const float* whhf = (const float*)d_in[3];
  const float* bihf = (const float*)d_in[4];
  const float* bhhf = (const float*)d_in[5];
  const float* wihb = (const float*)d_in[6];
  const float* whhb = (const float*)d_in[7];
  const float* bihb = (const float*)d_in[8];
  const float* bhhb = (const float*)d_in[9];
  const float* wtag = (const float*)d_in[10];
  const float* btag = (const float*)d_in[11];
  const float* trans = (const float*)d_in[12];

  float* ws = (float*)d_ws;
  float* X    = ws + OFF_X;
  float* WT   = ws + OFF_WT;
  float* BS   = ws + OFF_BSUM;
  float* Gf   = ws + OFF_GF;
  float* Gb   = ws + OFF_GB;
  float* HF   = ws + OFF_HF;
  float* HB   = ws + OFF_HB;
  float* FE   = ws + OFF_FEATS;
  unsigned char* bpg = (unsigned char*)(ws + OFF_BP);
  float* AC   = ws + OFF_AC;
  float* FVB  = ws + OFF_FVB;
  float* SB   = ws + OFF_SB;
  float* out = (float*)d_out;

  prep_k<<<1025, 256, 0, stream>>>(wihf, wihb, bihf, bhhf, bihb, bhhb, WT, BS);
  gather_k<<<SEQ, 64, 0, stream>>>(sent, emb, X);
  gemm_k<<<dim3(16, 128), 256, 0, stream>>>(X, WT, BS, Gf, Gb);
  lstm_k<<<2, 256, 0, stream>>>(whhf, whhb, Gf, Gb, HF, HB);
  feats_k<<<SEQ, 64, 0, stream>>>(HF, HB, wtag, btag, FE);
  vit_a<<<64, 256, 0, stream>>>(FE, trans, AC);
  vit_b<<<1, 64, 0, stream>>>(trans, AC, FVB, out, SB);
  vit_c<<<64, 64, 0, stream>>>(FE, trans, FVB, bpg);
  vit_d<<<1, 1024, 0, stream>>>(bpg, SB, out);
}